// Round 18
// baseline (293.170 us; speedup 1.0000x reference)
//
#include <hip/hip_runtime.h>

#define NN 100000
#define EE 1600000
#define IN_DIM 128
#define HID 64
#define NH 4
#define DH 16
#define NL 3
#define OUT_DIM 64
#define SLOPE 0.2f
#define LN_EPS 1e-5f
#define RB 4
#define ZSC 64.0f
#define ZISC 0.015625f

// bucket CSR build
#define BSH 9
#define BSZ 512
#define NB ((NN + BSZ - 1) / BSZ)             // 196
#define CAP 10240
#define CHUNK 4096
#define P1_BLOCKS ((EE + CHUNK - 1) / CHUNK)  // 391

using short8 = __attribute__((ext_vector_type(8))) short;
using f32x4  = __attribute__((ext_vector_type(4))) float;
using f32x2  = __attribute__((ext_vector_type(2))) float;

__device__ __forceinline__ float bcast(float x, int lane) {
    return __int_as_float(__builtin_amdgcn_readlane(__float_as_int(x), lane));
}
__device__ __forceinline__ unsigned f2bf(float x) {
    unsigned u = __float_as_uint(x);
    u += 0x7FFFu + ((u >> 16) & 1u);      // RNE
    return u >> 16;
}
__device__ __forceinline__ float bf2f(unsigned short b) {
    return __uint_as_float(((unsigned)b) << 16);
}
__device__ __forceinline__ float bflo(unsigned zp) {
    return __uint_as_float(zp << 16);
}
__device__ __forceinline__ float bfhi(unsigned zp) {
    return __uint_as_float(zp & 0xFFFF0000u);
}

__device__ float walv(const float* __restrict__ W, const float* __restrict__ al,
                      const float* __restrict__ ar, int k, int c) {
    if (c < 4) {
        float s = 0.f;
#pragma unroll
        for (int d = 0; d < 16; ++d) s += W[k * HID + c * 16 + d] * al[c * 16 + d];
        return s;
    }
    if (c < 8) {
        const int hh = c - 4;
        float s = 0.f;
#pragma unroll
        for (int d = 0; d < 16; ++d) s += W[k * HID + hh * 16 + d] * ar[hh * 16 + d];
        return s;
    }
    return 0.f;
}

// ---------------- merged prep: W_in pack (blocks 0-3), GAT W pack (4-12), zero (13) ----
__global__ __launch_bounds__(256)
void k_prep(const float* __restrict__ W_in, const float* __restrict__ W_gat,
            const float* __restrict__ a_l, const float* __restrict__ a_r,
            uint4* __restrict__ Wb, uint4* __restrict__ Wbg,
            int* __restrict__ bcnt, int* __restrict__ esrc_pad) {
    const int b = blockIdx.x;
    const int t = threadIdx.x;
    if (b < 4) {
        const int tid = b * 256 + t;
        const int lane = tid & 63;
        const int ntkk = tid >> 6;
        const int nt = ntkk & 3, kk = ntkk >> 2;
        const int k0 = kk * 32 + (lane >> 4) * 8;
        const int n  = nt * 16 + (lane & 15);
        unsigned dw[4];
#pragma unroll
        for (int p = 0; p < 4; ++p) {
            const unsigned lo = f2bf(W_in[(k0 + 2 * p) * HID + n]);
            const unsigned hi = f2bf(W_in[(k0 + 2 * p + 1) * HID + n]);
            dw[p] = lo | (hi << 16);
        }
        Wb[ntkk * 64 + lane] = make_uint4(dw[0], dw[1], dw[2], dw[3]);
    } else if (b < 13) {
        const int lb = b - 4;
        const int l = lb / 3;
        const int tid = (lb % 3) * 256 + t;
        if (tid < 640) {
            const int lane = tid & 63;
            const int f = tid >> 6;
            const int kk = f / 5, nt = f % 5;
            const float* W  = W_gat + (size_t)l * HID * HID;
            const float* al = a_l + (size_t)l * HID;
            const float* ar = a_r + (size_t)l * HID;
            const int k0 = kk * 32 + (lane >> 4) * 8;
            const int n  = lane & 15;
            unsigned dw[4];
#pragma unroll
            for (int p = 0; p < 4; ++p) {
                float b0, b1;
                if (nt < 4) {
                    b0 = W[(k0 + 2 * p) * HID + nt * 16 + n];
                    b1 = W[(k0 + 2 * p + 1) * HID + nt * 16 + n];
                } else {
                    b0 = walv(W, al, ar, k0 + 2 * p, n);
                    b1 = walv(W, al, ar, k0 + 2 * p + 1, n);
                }
                dw[p] = f2bf(b0) | (f2bf(b1) << 16);
            }
            Wbg[(size_t)l * 640 + f * 64 + lane] = make_uint4(dw[0], dw[1], dw[2], dw[3]);
        }
    } else {
        if (t < NB) bcnt[t] = 0;
        if (t < 32) esrc_pad[t] = 0;
    }
}

// h0(bf16) = X @ W_in + b_in via MFMA. h row-major bf16 [node][64].
__global__ __launch_bounds__(256)
void k_in_gemm(const float* __restrict__ X, const uint4* __restrict__ Wb,
               const float* __restrict__ b, unsigned* __restrict__ h32) {
    const int l  = threadIdx.x & 63;
    const int wv = threadIdx.x >> 6;
    const int wrow = blockIdx.x * 64 + wv * 16;
    if (wrow >= NN) return;
    const int arow = wrow + (l & 15);
    const int kb_off = (l >> 4) * 8;
    f32x4 acc[4];
#pragma unroll
    for (int nt = 0; nt < 4; ++nt) acc[nt] = (f32x4){0.f, 0.f, 0.f, 0.f};
    const float* xr = X + (size_t)arow * IN_DIM;
#pragma unroll
    for (int kk = 0; kk < 4; ++kk) {
        const int kb = kk * 32 + kb_off;
        const float4 xa = *(const float4*)(xr + kb);
        const float4 xb = *(const float4*)(xr + kb + 4);
        const unsigned d0 = f2bf(xa.x) | (f2bf(xa.y) << 16);
        const unsigned d1 = f2bf(xa.z) | (f2bf(xa.w) << 16);
        const unsigned d2 = f2bf(xb.x) | (f2bf(xb.y) << 16);
        const unsigned d3 = f2bf(xb.z) | (f2bf(xb.w) << 16);
        const uint4 au = make_uint4(d0, d1, d2, d3);
        const short8 af = __builtin_bit_cast(short8, au);
#pragma unroll
        for (int nt = 0; nt < 4; ++nt) {
            const uint4 bu = Wb[(kk * 4 + nt) * 64 + l];
            const short8 bf = __builtin_bit_cast(short8, bu);
            acc[nt] = __builtin_amdgcn_mfma_f32_16x16x32_bf16(af, bf, acc[nt], 0, 0, 0);
        }
    }
    const int grp = l >> 4, ci = l & 15;
#pragma unroll
    for (int nt = 0; nt < 4; ++nt) {
        const float bv = b[nt * 16 + ci];
#pragma unroll
        for (int r = 0; r < 4; ++r) {
            const int row = wrow + grp * 4 + r;
            const unsigned my = f2bf(acc[nt][r] + bv);
            const unsigned ot = (unsigned)__shfl_xor((int)my, 1, 64);
            if ((ci & 1) == 0)
                h32[(size_t)row * 32 + nt * 8 + (ci >> 1)] = my | (ot << 16);
        }
    }
}

// z(fp8 e4m3, scale 64) = h @ W + fused er via 5th MFMA N-tile (el recomputed in gat).
__global__ __launch_bounds__(256)
void k_zgemm(const unsigned short* __restrict__ h16, const uint4* __restrict__ Wbg,
             unsigned* __restrict__ zb8, float* __restrict__ er) {
    const int l  = threadIdx.x & 63;
    const int wv = threadIdx.x >> 6;
    const int wrow = blockIdx.x * 64 + wv * 16;
    if (wrow >= NN) return;
    const int arow = wrow + (l & 15);
    const int kb_off = (l >> 4) * 8;
    f32x4 acc[5];
#pragma unroll
    for (int nt = 0; nt < 5; ++nt) acc[nt] = (f32x4){0.f, 0.f, 0.f, 0.f};
#pragma unroll
    for (int kk = 0; kk < 2; ++kk) {
        const int kb = kk * 32 + kb_off;
        const uint4 au = *(const uint4*)(h16 + (size_t)arow * 64 + kb);
        const short8 af = __builtin_bit_cast(short8, au);
#pragma unroll
        for (int nt = 0; nt < 5; ++nt) {
            const uint4 bu = Wbg[(kk * 5 + nt) * 64 + l];
            const short8 bf = __builtin_bit_cast(short8, bu);
            acc[nt] = __builtin_amdgcn_mfma_f32_16x16x32_bf16(af, bf, acc[nt], 0, 0, 0);
        }
    }
    const int grp = l >> 4, ci = l & 15;
#pragma unroll
    for (int nt = 0; nt < 4; ++nt) {
#pragma unroll
        for (int r = 0; r < 4; ++r) {
            const int row = wrow + grp * 4 + r;
            const float v = acc[nt][r] * ZSC;
            const float vn = __shfl_xor(v, 1, 64);   // neighbor col
            unsigned pk = (unsigned)__builtin_amdgcn_cvt_pk_fp8_f32(v, vn, 0, false) & 0xFFFFu;
            const unsigned pk2 = (unsigned)__shfl_xor((int)pk, 2, 64);
            pk |= pk2 << 16;
            if ((ci & 3) == 0)
                zb8[(size_t)row * 16 + nt * 4 + (ci >> 2)] = pk;
        }
    }
#pragma unroll
    for (int r = 0; r < 4; ++r) {
        const int row = wrow + grp * 4 + r;
        const float v = acc[4][r];
        if (ci >= 4 && ci < 8) er[row * NH + (ci - 4)] = v;
    }
}

// ---------------- bucket-sort CSR build ----------------

__global__ __launch_bounds__(256)
void k_bucketize(const int* __restrict__ src, const int* __restrict__ dst,
                 int* __restrict__ bcnt, unsigned* __restrict__ bbuf) {
    __shared__ int lh[256];
    __shared__ int lbase[256];
    __shared__ int lcnt[256];
    __shared__ int gbase[256];
    __shared__ int sc[256];
    __shared__ unsigned stage[CHUNK];      // 16 KB
    __shared__ unsigned char sbkt[CHUNK];  // 4 KB
    const int t = threadIdx.x;
    const int e0 = blockIdx.x * CHUNK;
    const int n = min(CHUNK, EE - e0);
    lh[t] = 0;
    __syncthreads();
    int myd[CHUNK / 256], mys[CHUNK / 256];
#pragma unroll
    for (int i = 0; i < CHUNK / 256; ++i) {
        const int o = i * 256 + t;
        if (o < n) {
            myd[i] = dst[e0 + o];
            mys[i] = src[e0 + o];
            atomicAdd(&lh[myd[i] >> BSH], 1);
        } else myd[i] = -1;
    }
    __syncthreads();
    {
        const int v = lh[t];
        lcnt[t] = v;
        sc[t] = v;
        __syncthreads();
        for (int off = 1; off < 256; off <<= 1) {
            const int x = (t >= off) ? sc[t - off] : 0;
            __syncthreads();
            sc[t] += x;
            __syncthreads();
        }
        lbase[t] = sc[t] - v;
        lh[t] = sc[t] - v;
    }
    __syncthreads();
#pragma unroll
    for (int i = 0; i < CHUNK / 256; ++i) {
        if (myd[i] >= 0) {
            const int b = myd[i] >> BSH;
            const int p = atomicAdd(&lh[b], 1);
            stage[p] = (unsigned)mys[i] | (((unsigned)myd[i] & 511u) << 17);
            sbkt[p] = (unsigned char)b;
        }
    }
    __syncthreads();
    if (t < NB && lcnt[t] > 0) gbase[t] = atomicAdd(&bcnt[t], lcnt[t]);
    __syncthreads();
    for (int i = t; i < n; i += 256) {
        const int b = sbkt[i];
        const int gp = gbase[b] + (i - lbase[b]);
        if (gp < CAP) bbuf[(size_t)b * CAP + gp] = stage[i];
    }
}

__global__ __launch_bounds__(256)
void k_localcsr(const int* __restrict__ bcnt, const unsigned* __restrict__ bbuf,
                int* __restrict__ rowptr, int* __restrict__ esrc) {
    const int b = blockIdx.x;
    const int t = threadIdx.x;
    __shared__ int sc[256];
    __shared__ int s_base;
    {
        const int v = (t < NB) ? bcnt[t] : 0;
        sc[t] = v;
        __syncthreads();
        for (int off = 1; off < 256; off <<= 1) {
            const int x = (t >= off) ? sc[t - off] : 0;
            __syncthreads();
            sc[t] += x;
            __syncthreads();
        }
        if (t == 0) {
            s_base = sc[b] - bcnt[b];
            if (b == 0) rowptr[NN] = EE;
        }
        __syncthreads();
    }
    const int cnt = bcnt[b];
    const int base = s_base;
    const int n0 = b * BSZ;
    const int nn = min(BSZ, NN - n0);
    __shared__ int lh[BSZ];
    __shared__ int lsc[BSZ];
    for (int i = t; i < BSZ; i += 256) lh[i] = 0;
    __syncthreads();
    const unsigned* bb = bbuf + (size_t)b * CAP;
    for (int i = t; i < cnt; i += 256) atomicAdd(&lh[(bb[i] >> 17) & 511u], 1);
    __syncthreads();
    const int a0 = lh[2 * t], a1 = lh[2 * t + 1];
    const int ts = a0 + a1;
    sc[t] = ts;
    __syncthreads();
    for (int off = 1; off < 256; off <<= 1) {
        const int x = (t >= off) ? sc[t - off] : 0;
        __syncthreads();
        sc[t] += x;
        __syncthreads();
    }
    const int ebase = sc[t] - ts;
    lsc[2 * t] = ebase;
    lsc[2 * t + 1] = ebase + a0;
    __syncthreads();
    for (int i = t; i < BSZ; i += 256) {
        if (i < nn) rowptr[n0 + i] = base + lsc[i];
        lh[i] = lsc[i];
    }
    __syncthreads();
    for (int i = t; i < cnt; i += 256) {
        const unsigned en = bb[i];
        const int p = atomicAdd(&lh[(en >> 17) & 511u], 1);
        esrc[base + p] = (int)(en & 0x1FFFFu);
    }
}

// ---------------- fused per-dst GAT layer: DUAL-dst per wave, fp8 z, el-from-z ----
// Each wave handles dst pair (d0, d0+1) with two independent depth-2 pipelines:
// ILP/MLP doubles, per-wave prologue overhead halves. Clamped esrc indices keep
// the joint loop safe when one dst finishes early.
__global__ __launch_bounds__(256)
void k_gat_dst(const int* __restrict__ rowptr, const int* __restrict__ esrc,
               const float* __restrict__ al, const float* __restrict__ er,
               const uint2* __restrict__ zb64, const unsigned short* __restrict__ hin16,
               const float* __restrict__ bg, unsigned* __restrict__ hout32) {
    const int j  = threadIdx.x & 63;
    const int wv = threadIdx.x >> 6;
    const int d0 = (blockIdx.x * 4 + wv) * 2;
    if (d0 >= NN) return;
    const int d1 = d0 + 1;
    const int g = j >> 3;
    const int q = j & 7;
    const int hh = q >> 1;
    const int r0a = rowptr[d0];
    const int r1a = rowptr[d1];      // == rowptr[d0+1]
    const int r1b = rowptr[d1 + 1];
    const int r0b = r1a;
    const float era = er[d0 * NH + hh];
    const float erb = er[d1 * NH + hh];
    const float4 alA = *(const float4*)(al + 8 * q);
    const float4 alB = *(const float4*)(al + 8 * q + 4);
    uint4 hva = make_uint4(0, 0, 0, 0), hvb = make_uint4(0, 0, 0, 0);
    if (g == 0) {
        hva = *(const uint4*)(hin16 + (size_t)d0 * 64 + 8 * q);
        hvb = *(const uint4*)(hin16 + (size_t)d1 * 64 + 8 * q);
    }
    float a0 = 0.f, a1 = 0.f, a2 = 0.f, a3 = 0.f;
    float a4 = 0.f, a5 = 0.f, a6 = 0.f, a7 = 0.f, dena = 0.f;
    float b0 = 0.f, b1 = 0.f, b2 = 0.f, b3 = 0.f;
    float b4 = 0.f, b5 = 0.f, b6 = 0.f, b7 = 0.f, denb = 0.f;
    // two depth-2 pipelines (z prefetched 1 iter ahead; ids clamped to r1)
    unsigned sa = (unsigned)esrc[min(r0a + g, r1a)];
    uint2 za = zb64[sa * 8u + q];
    unsigned sa1 = (unsigned)esrc[min(r0a + 8 + g, r1a)];
    unsigned sb = (unsigned)esrc[min(r0b + g, r1b)];
    uint2 zb = zb64[sb * 8u + q];
    unsigned sb1 = (unsigned)esrc[min(r0b + 8 + g, r1b)];
    int ia = r0a, ib = r0b;
    while (ia < r1a || ib < r1b) {
        const uint2 zaN = zb64[sa1 * 8u + q];
        const uint2 zbN = zb64[sb1 * 8u + q];
        const unsigned sa2 = (unsigned)esrc[min(ia + 16 + g, r1a)];
        const unsigned sb2 = (unsigned)esrc[min(ib + 16 + g, r1b)];
        // consume dst0 batch
        {
            const f32x2 p0 = __builtin_amdgcn_cvt_pk_f32_fp8(za.x, false);
            const f32x2 p1 = __builtin_amdgcn_cvt_pk_f32_fp8(za.x, true);
            const f32x2 p2 = __builtin_amdgcn_cvt_pk_f32_fp8(za.y, false);
            const f32x2 p3 = __builtin_amdgcn_cvt_pk_f32_fp8(za.y, true);
            float dot = p0.x * alA.x + p0.y * alA.y + p1.x * alA.z + p1.y * alA.w
                      + p2.x * alB.x + p2.y * alB.y + p3.x * alB.z + p3.y * alB.w;
            dot += __shfl_xor(dot, 1, 64);
            const float x = dot * ZISC + era;
            float w = __expf(fmaxf(x, SLOPE * x));
            w = (ia + g < r1a) ? w : 0.f;
            dena += w;
            a0 = fmaf(w, p0.x, a0); a1 = fmaf(w, p0.y, a1);
            a2 = fmaf(w, p1.x, a2); a3 = fmaf(w, p1.y, a3);
            a4 = fmaf(w, p2.x, a4); a5 = fmaf(w, p2.y, a5);
            a6 = fmaf(w, p3.x, a6); a7 = fmaf(w, p3.y, a7);
        }
        // consume dst1 batch
        {
            const f32x2 p0 = __builtin_amdgcn_cvt_pk_f32_fp8(zb.x, false);
            const f32x2 p1 = __builtin_amdgcn_cvt_pk_f32_fp8(zb.x, true);
            const f32x2 p2 = __builtin_amdgcn_cvt_pk_f32_fp8(zb.y, false);
            const f32x2 p3 = __builtin_amdgcn_cvt_pk_f32_fp8(zb.y, true);
            float dot = p0.x * alA.x + p0.y * alA.y + p1.x * alA.z + p1.y * alA.w
                      + p2.x * alB.x + p2.y * alB.y + p3.x * alB.z + p3.y * alB.w;
            dot += __shfl_xor(dot, 1, 64);
            const float x = dot * ZISC + erb;
            float w = __expf(fmaxf(x, SLOPE * x));
            w = (ib + g < r1b) ? w : 0.f;
            denb += w;
            b0 = fmaf(w, p0.x, b0); b1 = fmaf(w, p0.y, b1);
            b2 = fmaf(w, p1.x, b2); b3 = fmaf(w, p1.y, b3);
            b4 = fmaf(w, p2.x, b4); b5 = fmaf(w, p2.y, b5);
            b6 = fmaf(w, p3.x, b6); b7 = fmaf(w, p3.y, b7);
        }
        za = zaN; sa1 = sa2;
        zb = zbN; sb1 = sb2;
        ia += 8; ib += 8;
    }
#pragma unroll
    for (int m = 8; m <= 32; m <<= 1) {
        dena += __shfl_xor(dena, m, 64);
        a0 += __shfl_xor(a0, m, 64); a1 += __shfl_xor(a1, m, 64);
        a2 += __shfl_xor(a2, m, 64); a3 += __shfl_xor(a3, m, 64);
        a4 += __shfl_xor(a4, m, 64); a5 += __shfl_xor(a5, m, 64);
        a6 += __shfl_xor(a6, m, 64); a7 += __shfl_xor(a7, m, 64);
        denb += __shfl_xor(denb, m, 64);
        b0 += __shfl_xor(b0, m, 64); b1 += __shfl_xor(b1, m, 64);
        b2 += __shfl_xor(b2, m, 64); b3 += __shfl_xor(b3, m, 64);
        b4 += __shfl_xor(b4, m, 64); b5 += __shfl_xor(b5, m, 64);
        b6 += __shfl_xor(b6, m, 64); b7 += __shfl_xor(b7, m, 64);
    }
    if (g == 0) {
        const int c = 8 * q;
        const float bg0 = bg[c + 0], bg1 = bg[c + 1], bg2 = bg[c + 2], bg3 = bg[c + 3];
        const float bg4 = bg[c + 4], bg5 = bg[c + 5], bg6 = bg[c + 6], bg7 = bg[c + 7];
        // dst0
        {
            float o0 = bflo(hva.x) + bg0, o1 = bfhi(hva.x) + bg1;
            float o2 = bflo(hva.y) + bg2, o3 = bfhi(hva.y) + bg3;
            float o4 = bflo(hva.z) + bg4, o5 = bfhi(hva.z) + bg5;
            float o6 = bflo(hva.w) + bg6, o7 = bfhi(hva.w) + bg7;
            if (r1a > r0a) {
                const float rds = (1.f / dena) * ZISC;
                o0 = fmaf(a0, rds, o0); o1 = fmaf(a1, rds, o1);
                o2 = fmaf(a2, rds, o2); o3 = fmaf(a3, rds, o3);
                o4 = fmaf(a4, rds, o4); o5 = fmaf(a5, rds, o5);
                o6 = fmaf(a6, rds, o6); o7 = fmaf(a7, rds, o7);
            }
            const uint4 ov = make_uint4(f2bf(o0) | (f2bf(o1) << 16),
                                        f2bf(o2) | (f2bf(o3) << 16),
                                        f2bf(o4) | (f2bf(o5) << 16),
                                        f2bf(o6) | (f2bf(o7) << 16));
            *(uint4*)(hout32 + (size_t)d0 * 32 + 4 * q) = ov;
        }
        // dst1
        {
            float o0 = bflo(hvb.x) + bg0, o1 = bfhi(hvb.x) + bg1;
            float o2 = bflo(hvb.y) + bg2, o3 = bfhi(hvb.y) + bg3;
            float o4 = bflo(hvb.z) + bg4, o5 = bfhi(hvb.z) + bg5;
            float o6 = bflo(hvb.w) + bg6, o7 = bfhi(hvb.w) + bg7;
            if (r1b > r0b) {
                const float rds = (1.f / denb) * ZISC;
                o0 = fmaf(b0, rds, o0); o1 = fmaf(b1, rds, o1);
                o2 = fmaf(b2, rds, o2); o3 = fmaf(b3, rds, o3);
                o4 = fmaf(b4, rds, o4); o5 = fmaf(b5, rds, o5);
                o6 = fmaf(b6, rds, o6); o7 = fmaf(b7, rds, o7);
            }
            const uint4 ov = make_uint4(f2bf(o0) | (f2bf(o1) << 16),
                                        f2bf(o2) | (f2bf(o3) << 16),
                                        f2bf(o4) | (f2bf(o5) << 16),
                                        f2bf(o6) | (f2bf(o7) << 16));
            *(uint4*)(hout32 + (size_t)d1 * 32 + 4 * q) = ov;
        }
    }
}

// LayerNorm + out = hn @ W_out + b_out. W column in registers; h bf16 in.
__global__ __launch_bounds__(256, 4)
void k_ln_out(const unsigned short* __restrict__ h16, const float* __restrict__ g,
              const float* __restrict__ be, const float* __restrict__ Wo,
              const float* __restrict__ bo, float* __restrict__ out) {
    const int j = threadIdx.x & 63;
    float Wreg[HID];
#pragma unroll
    for (int k = 0; k < HID; ++k) Wreg[k] = Wo[k * OUT_DIM + j];
    const float gj = g[j], bej = be[j], boj = bo[j];
    const int wid = (blockIdx.x * blockDim.x + threadIdx.x) >> 6;
    const int nw  = (gridDim.x * blockDim.x) >> 6;
    for (int v0 = wid * RB; v0 < NN; v0 += nw * RB) {
        float hn[RB];
#pragma unroll
        for (int r = 0; r < RB; ++r) {
            const float x = bf2f(h16[(size_t)(v0 + r) * HID + j]);
            float s = x;
#pragma unroll
            for (int m = 32; m >= 1; m >>= 1) s += __shfl_xor(s, m, 64);
            const float mu = s * (1.f / 64.f);
            const float dx = x - mu;
            float vs = dx * dx;
#pragma unroll
            for (int m = 32; m >= 1; m >>= 1) vs += __shfl_xor(vs, m, 64);
            hn[r] = dx * rsqrtf(vs * (1.f / 64.f) + LN_EPS) * gj + bej;
        }
        float acc[RB];
#pragma unroll
        for (int r = 0; r < RB; ++r) acc[r] = boj;
#pragma unroll
        for (int k = 0; k < HID; ++k) {
#pragma unroll
            for (int r = 0; r < RB; ++r)
                acc[r] = fmaf(bcast(hn[r], k), Wreg[k], acc[r]);
        }
#pragma unroll
        for (int r = 0; r < RB; ++r) out[(size_t)(v0 + r) * OUT_DIM + j] = acc[r];
    }
}

extern "C" void kernel_launch(void* const* d_in, const int* in_sizes, int n_in,
                              void* d_out, int out_size, void* d_ws, size_t ws_size,
                              hipStream_t stream) {
    const float* X     = (const float*)d_in[0];
    const int*   src   = (const int*)d_in[1];
    const int*   dst   = (const int*)d_in[2];
    const float* W_in  = (const float*)d_in[3];
    const float* b_in  = (const float*)d_in[4];
    // d_in[5..8]: rewiring MLP params — output is dead, skipped entirely
    const float* W_gat = (const float*)d_in[9];
    const float* a_l   = (const float*)d_in[10];
    const float* a_r   = (const float*)d_in[11];
    const float* b_gat = (const float*)d_in[12];
    const float* ln_g  = (const float*)d_in[13];
    const float* ln_b  = (const float*)d_in[14];
    const float* W_out = (const float*)d_in[15];
    const float* b_out = (const float*)d_in[16];
    float* out = (float*)d_out;

    char* ws = (char*)d_ws;
    unsigned short* hA16 = (unsigned short*)ws;                    // N*64 bf16 (12.8MB)
    unsigned short* hB16 = hA16 + (size_t)NN * HID;                // N*64 bf16 (12.8MB)
    unsigned* zb8 = (unsigned*)(hB16 + (size_t)NN * HID);          // N*16 dwords fp8 (6.4MB)
    float* er = (float*)(zb8 + (size_t)NN * 16);                   // N*4
    int* rowptr = (int*)(er + (size_t)NN * NH);                    // N+1
    int* esrc   = rowptr + NN + 1;                                 // E + 32 (padded)
    int* bcnt   = esrc + EE + 32;
    uintptr_t wp = (uintptr_t)(bcnt + NB);
    wp = (wp + 15) & ~(uintptr_t)15;
    uint4* Wb   = (uint4*)wp;                                      // 16 KB
    uint4* Wbg  = Wb + 1024;                                       // 30 KB
    unsigned* bbuf = (unsigned*)hB16;   // aliases hB16 (dead until after CSR build)

    k_prep<<<14, 256, 0, stream>>>(W_in, W_gat, a_l, a_r, Wb, Wbg, bcnt, esrc + EE);
    k_in_gemm<<<(NN + 63) / 64, 256, 0, stream>>>(X, Wb, b_in, (unsigned*)hA16);
    k_bucketize<<<P1_BLOCKS, 256, 0, stream>>>(src, dst, bcnt, bbuf);
    k_localcsr<<<NB, 256, 0, stream>>>(bcnt, bbuf, rowptr, esrc);

    unsigned short* hin = hA16;
    unsigned short* hout = hB16;
    for (int l = 0; l < NL; ++l) {
        k_zgemm<<<(NN + 63) / 64, 256, 0, stream>>>(hin, Wbg + (size_t)l * 640,
                                                    zb8, er);
        k_gat_dst<<<(NN + 7) / 8, 256, 0, stream>>>(rowptr, esrc,
                                                    a_l + (size_t)l * HID, er,
                                                    (const uint2*)zb8, hin,
                                                    b_gat + (size_t)l * HID,
                                                    (unsigned*)hout);
        unsigned short* t = hin; hin = hout; hout = t;
    }

    k_ln_out<<<1024, 256, 0, stream>>>(hin, ln_g, ln_b, W_out, b_out, out);
}

// Round 19
// 288.777 us; speedup vs baseline: 1.0152x; 1.0152x over previous
//
#include <hip/hip_runtime.h>

#define NN 100000
#define EE 1600000
#define IN_DIM 128
#define HID 64
#define NH 4
#define DH 16
#define NL 3
#define OUT_DIM 64
#define SLOPE 0.2f
#define LN_EPS 1e-5f
#define RB 4
#define ZSC 64.0f
#define ZISC 0.015625f

// bucket CSR build
#define BSH 9
#define BSZ 512
#define NB ((NN + BSZ - 1) / BSZ)             // 196
#define CAP 10240
#define CHUNK 4096
#define P1_BLOCKS ((EE + CHUNK - 1) / CHUNK)  // 391

using short8 = __attribute__((ext_vector_type(8))) short;
using f32x4  = __attribute__((ext_vector_type(4))) float;
using f32x2  = __attribute__((ext_vector_type(2))) float;

__device__ __forceinline__ float bcast(float x, int lane) {
    return __int_as_float(__builtin_amdgcn_readlane(__float_as_int(x), lane));
}
__device__ __forceinline__ unsigned f2bf(float x) {
    unsigned u = __float_as_uint(x);
    u += 0x7FFFu + ((u >> 16) & 1u);      // RNE
    return u >> 16;
}
__device__ __forceinline__ float bf2f(unsigned short b) {
    return __uint_as_float(((unsigned)b) << 16);
}
__device__ __forceinline__ float bflo(unsigned zp) {
    return __uint_as_float(zp << 16);
}
__device__ __forceinline__ float bfhi(unsigned zp) {
    return __uint_as_float(zp & 0xFFFF0000u);
}

__device__ float walv(const float* __restrict__ W, const float* __restrict__ al,
                      const float* __restrict__ ar, int k, int c) {
    if (c < 4) {
        float s = 0.f;
#pragma unroll
        for (int d = 0; d < 16; ++d) s += W[k * HID + c * 16 + d] * al[c * 16 + d];
        return s;
    }
    if (c < 8) {
        const int hh = c - 4;
        float s = 0.f;
#pragma unroll
        for (int d = 0; d < 16; ++d) s += W[k * HID + hh * 16 + d] * ar[hh * 16 + d];
        return s;
    }
    return 0.f;
}

// ---------------- merged prep: W_in pack (blocks 0-3), GAT W pack (4-12), zero (13) ----
__global__ __launch_bounds__(256)
void k_prep(const float* __restrict__ W_in, const float* __restrict__ W_gat,
            const float* __restrict__ a_l, const float* __restrict__ a_r,
            uint4* __restrict__ Wb, uint4* __restrict__ Wbg,
            int* __restrict__ bcnt, int* __restrict__ esrc_pad) {
    const int b = blockIdx.x;
    const int t = threadIdx.x;
    if (b < 4) {
        const int tid = b * 256 + t;
        const int lane = tid & 63;
        const int ntkk = tid >> 6;
        const int nt = ntkk & 3, kk = ntkk >> 2;
        const int k0 = kk * 32 + (lane >> 4) * 8;
        const int n  = nt * 16 + (lane & 15);
        unsigned dw[4];
#pragma unroll
        for (int p = 0; p < 4; ++p) {
            const unsigned lo = f2bf(W_in[(k0 + 2 * p) * HID + n]);
            const unsigned hi = f2bf(W_in[(k0 + 2 * p + 1) * HID + n]);
            dw[p] = lo | (hi << 16);
        }
        Wb[ntkk * 64 + lane] = make_uint4(dw[0], dw[1], dw[2], dw[3]);
    } else if (b < 13) {
        const int lb = b - 4;
        const int l = lb / 3;
        const int tid = (lb % 3) * 256 + t;
        if (tid < 640) {
            const int lane = tid & 63;
            const int f = tid >> 6;
            const int kk = f / 5, nt = f % 5;
            const float* W  = W_gat + (size_t)l * HID * HID;
            const float* al = a_l + (size_t)l * HID;
            const float* ar = a_r + (size_t)l * HID;
            const int k0 = kk * 32 + (lane >> 4) * 8;
            const int n  = lane & 15;
            unsigned dw[4];
#pragma unroll
            for (int p = 0; p < 4; ++p) {
                float b0, b1;
                if (nt < 4) {
                    b0 = W[(k0 + 2 * p) * HID + nt * 16 + n];
                    b1 = W[(k0 + 2 * p + 1) * HID + nt * 16 + n];
                } else {
                    b0 = walv(W, al, ar, k0 + 2 * p, n);
                    b1 = walv(W, al, ar, k0 + 2 * p + 1, n);
                }
                dw[p] = f2bf(b0) | (f2bf(b1) << 16);
            }
            Wbg[(size_t)l * 640 + f * 64 + lane] = make_uint4(dw[0], dw[1], dw[2], dw[3]);
        }
    } else {
        if (t < NB) bcnt[t] = 0;
        if (t < 32) esrc_pad[t] = 0;
    }
}

// h0(bf16) = X @ W_in + b_in via MFMA. h row-major bf16 [node][64].
__global__ __launch_bounds__(256)
void k_in_gemm(const float* __restrict__ X, const uint4* __restrict__ Wb,
               const float* __restrict__ b, unsigned* __restrict__ h32) {
    const int l  = threadIdx.x & 63;
    const int wv = threadIdx.x >> 6;
    const int wrow = blockIdx.x * 64 + wv * 16;
    if (wrow >= NN) return;
    const int arow = wrow + (l & 15);
    const int kb_off = (l >> 4) * 8;
    f32x4 acc[4];
#pragma unroll
    for (int nt = 0; nt < 4; ++nt) acc[nt] = (f32x4){0.f, 0.f, 0.f, 0.f};
    const float* xr = X + (size_t)arow * IN_DIM;
#pragma unroll
    for (int kk = 0; kk < 4; ++kk) {
        const int kb = kk * 32 + kb_off;
        const float4 xa = *(const float4*)(xr + kb);
        const float4 xb = *(const float4*)(xr + kb + 4);
        const unsigned d0 = f2bf(xa.x) | (f2bf(xa.y) << 16);
        const unsigned d1 = f2bf(xa.z) | (f2bf(xa.w) << 16);
        const unsigned d2 = f2bf(xb.x) | (f2bf(xb.y) << 16);
        const unsigned d3 = f2bf(xb.z) | (f2bf(xb.w) << 16);
        const uint4 au = make_uint4(d0, d1, d2, d3);
        const short8 af = __builtin_bit_cast(short8, au);
#pragma unroll
        for (int nt = 0; nt < 4; ++nt) {
            const uint4 bu = Wb[(kk * 4 + nt) * 64 + l];
            const short8 bf = __builtin_bit_cast(short8, bu);
            acc[nt] = __builtin_amdgcn_mfma_f32_16x16x32_bf16(af, bf, acc[nt], 0, 0, 0);
        }
    }
    const int grp = l >> 4, ci = l & 15;
#pragma unroll
    for (int nt = 0; nt < 4; ++nt) {
        const float bv = b[nt * 16 + ci];
#pragma unroll
        for (int r = 0; r < 4; ++r) {
            const int row = wrow + grp * 4 + r;
            const unsigned my = f2bf(acc[nt][r] + bv);
            const unsigned ot = (unsigned)__shfl_xor((int)my, 1, 64);
            if ((ci & 1) == 0)
                h32[(size_t)row * 32 + nt * 8 + (ci >> 1)] = my | (ot << 16);
        }
    }
}

// z(fp8 e4m3, scale 64) = h @ W + fused el/er via 5th MFMA N-tile.
__global__ __launch_bounds__(256)
void k_zgemm(const unsigned short* __restrict__ h16, const uint4* __restrict__ Wbg,
             unsigned* __restrict__ zb8, float* __restrict__ el, float* __restrict__ er) {
    const int l  = threadIdx.x & 63;
    const int wv = threadIdx.x >> 6;
    const int wrow = blockIdx.x * 64 + wv * 16;
    if (wrow >= NN) return;
    const int arow = wrow + (l & 15);
    const int kb_off = (l >> 4) * 8;
    f32x4 acc[5];
#pragma unroll
    for (int nt = 0; nt < 5; ++nt) acc[nt] = (f32x4){0.f, 0.f, 0.f, 0.f};
#pragma unroll
    for (int kk = 0; kk < 2; ++kk) {
        const int kb = kk * 32 + kb_off;
        const uint4 au = *(const uint4*)(h16 + (size_t)arow * 64 + kb);
        const short8 af = __builtin_bit_cast(short8, au);
#pragma unroll
        for (int nt = 0; nt < 5; ++nt) {
            const uint4 bu = Wbg[(kk * 5 + nt) * 64 + l];
            const short8 bf = __builtin_bit_cast(short8, bu);
            acc[nt] = __builtin_amdgcn_mfma_f32_16x16x32_bf16(af, bf, acc[nt], 0, 0, 0);
        }
    }
    const int grp = l >> 4, ci = l & 15;
    // z -> fp8 pairs: lane pairs pack 2 cols via HW cvt, then merge to dwords
#pragma unroll
    for (int nt = 0; nt < 4; ++nt) {
#pragma unroll
        for (int r = 0; r < 4; ++r) {
            const int row = wrow + grp * 4 + r;
            const float v = acc[nt][r] * ZSC;
            const float vn = __shfl_xor(v, 1, 64);   // neighbor col
            unsigned pk = (unsigned)__builtin_amdgcn_cvt_pk_fp8_f32(v, vn, 0, false) & 0xFFFFu;
            const unsigned pk2 = (unsigned)__shfl_xor((int)pk, 2, 64);
            pk |= pk2 << 16;
            if ((ci & 3) == 0)
                zb8[(size_t)row * 16 + nt * 4 + (ci >> 2)] = pk;
        }
    }
#pragma unroll
    for (int r = 0; r < 4; ++r) {
        const int row = wrow + grp * 4 + r;
        const float v = acc[4][r];
        if (ci < 4) el[row * NH + ci] = v;
        else if (ci < 8) er[row * NH + (ci - 4)] = v;
    }
}

// ---------------- bucket-sort CSR build ----------------

__global__ __launch_bounds__(256)
void k_bucketize(const int* __restrict__ src, const int* __restrict__ dst,
                 int* __restrict__ bcnt, unsigned* __restrict__ bbuf) {
    __shared__ int lh[256];
    __shared__ int lbase[256];
    __shared__ int lcnt[256];
    __shared__ int gbase[256];
    __shared__ int sc[256];
    __shared__ unsigned stage[CHUNK];      // 16 KB
    __shared__ unsigned char sbkt[CHUNK];  // 4 KB
    const int t = threadIdx.x;
    const int e0 = blockIdx.x * CHUNK;
    const int n = min(CHUNK, EE - e0);
    lh[t] = 0;
    __syncthreads();
    int myd[CHUNK / 256], mys[CHUNK / 256];
#pragma unroll
    for (int i = 0; i < CHUNK / 256; ++i) {
        const int o = i * 256 + t;
        if (o < n) {
            myd[i] = dst[e0 + o];
            mys[i] = src[e0 + o];
            atomicAdd(&lh[myd[i] >> BSH], 1);
        } else myd[i] = -1;
    }
    __syncthreads();
    {
        const int v = lh[t];
        lcnt[t] = v;
        sc[t] = v;
        __syncthreads();
        for (int off = 1; off < 256; off <<= 1) {
            const int x = (t >= off) ? sc[t - off] : 0;
            __syncthreads();
            sc[t] += x;
            __syncthreads();
        }
        lbase[t] = sc[t] - v;
        lh[t] = sc[t] - v;
    }
    __syncthreads();
#pragma unroll
    for (int i = 0; i < CHUNK / 256; ++i) {
        if (myd[i] >= 0) {
            const int b = myd[i] >> BSH;
            const int p = atomicAdd(&lh[b], 1);
            stage[p] = (unsigned)mys[i] | (((unsigned)myd[i] & 511u) << 17);
            sbkt[p] = (unsigned char)b;
        }
    }
    __syncthreads();
    if (t < NB && lcnt[t] > 0) gbase[t] = atomicAdd(&bcnt[t], lcnt[t]);
    __syncthreads();
    for (int i = t; i < n; i += 256) {
        const int b = sbkt[i];
        const int gp = gbase[b] + (i - lbase[b]);
        if (gp < CAP) bbuf[(size_t)b * CAP + gp] = stage[i];
    }
}

__global__ __launch_bounds__(256)
void k_localcsr(const int* __restrict__ bcnt, const unsigned* __restrict__ bbuf,
                int* __restrict__ rowptr, int* __restrict__ esrc) {
    const int b = blockIdx.x;
    const int t = threadIdx.x;
    __shared__ int sc[256];
    __shared__ int s_base;
    {
        const int v = (t < NB) ? bcnt[t] : 0;
        sc[t] = v;
        __syncthreads();
        for (int off = 1; off < 256; off <<= 1) {
            const int x = (t >= off) ? sc[t - off] : 0;
            __syncthreads();
            sc[t] += x;
            __syncthreads();
        }
        if (t == 0) {
            s_base = sc[b] - bcnt[b];
            if (b == 0) rowptr[NN] = EE;
        }
        __syncthreads();
    }
    const int cnt = bcnt[b];
    const int base = s_base;
    const int n0 = b * BSZ;
    const int nn = min(BSZ, NN - n0);
    __shared__ int lh[BSZ];
    __shared__ int lsc[BSZ];
    for (int i = t; i < BSZ; i += 256) lh[i] = 0;
    __syncthreads();
    const unsigned* bb = bbuf + (size_t)b * CAP;
    for (int i = t; i < cnt; i += 256) atomicAdd(&lh[(bb[i] >> 17) & 511u], 1);
    __syncthreads();
    const int a0 = lh[2 * t], a1 = lh[2 * t + 1];
    const int ts = a0 + a1;
    sc[t] = ts;
    __syncthreads();
    for (int off = 1; off < 256; off <<= 1) {
        const int x = (t >= off) ? sc[t - off] : 0;
        __syncthreads();
        sc[t] += x;
        __syncthreads();
    }
    const int ebase = sc[t] - ts;
    lsc[2 * t] = ebase;
    lsc[2 * t + 1] = ebase + a0;
    __syncthreads();
    for (int i = t; i < BSZ; i += 256) {
        if (i < nn) rowptr[n0 + i] = base + lsc[i];
        lh[i] = lsc[i];
    }
    __syncthreads();
    for (int i = t; i < cnt; i += 256) {
        const unsigned en = bb[i];
        const int p = atomicAdd(&lh[(en >> 17) & 511u], 1);
        esrc[base + p] = (int)(en & 0x1FFFFu);
    }
}

// ---------------- fused per-dst GAT layer: eighth-wave, fp8 z, el-table, depth-2 ----
// (best-measured variant, round 15: 53.1 us)
__global__ __launch_bounds__(256)
void k_gat_dst(const int* __restrict__ rowptr, const int* __restrict__ esrc,
               const float* __restrict__ el, const float* __restrict__ er,
               const uint2* __restrict__ zb64, const unsigned short* __restrict__ hin16,
               const float* __restrict__ bg, unsigned* __restrict__ hout32) {
    const int j  = threadIdx.x & 63;
    const int wv = threadIdx.x >> 6;
    const int d = blockIdx.x * 4 + wv;
    if (d >= NN) return;
    const int g = j >> 3;
    const int q = j & 7;
    const int hh = q >> 1;
    const int r0 = rowptr[d], r1 = rowptr[d + 1];
    const float erh = er[d * NH + hh];
    uint4 hv4 = make_uint4(0, 0, 0, 0);
    if (g == 0) hv4 = *(const uint4*)(hin16 + (size_t)d * 64 + 8 * q);
    float a0 = 0.f, a1 = 0.f, a2 = 0.f, a3 = 0.f;
    float a4 = 0.f, a5 = 0.f, a6 = 0.f, a7 = 0.f;
    float den = 0.f;
    unsigned sA = (unsigned)esrc[r0 + g];
    float avA = el[sA * NH + hh];
    uint2 zpA = zb64[sA * 8u + q];
    unsigned sB = (unsigned)esrc[r0 + 8 + g];
    for (int i = r0; i < r1; i += 8) {
        const float avB = el[sB * NH + hh];
        const uint2 zpB = zb64[sB * 8u + q];
        const unsigned sC = (unsigned)esrc[i + 16 + g];   // pad-32 safe
        const float x = avA + erh;
        float w = __expf(fmaxf(x, SLOPE * x));
        w = (i + g < r1) ? w : 0.f;
        den += w;
        const f32x2 p0 = __builtin_amdgcn_cvt_pk_f32_fp8(zpA.x, false);
        const f32x2 p1 = __builtin_amdgcn_cvt_pk_f32_fp8(zpA.x, true);
        const f32x2 p2 = __builtin_amdgcn_cvt_pk_f32_fp8(zpA.y, false);
        const f32x2 p3 = __builtin_amdgcn_cvt_pk_f32_fp8(zpA.y, true);
        a0 = fmaf(w, p0.x, a0);
        a1 = fmaf(w, p0.y, a1);
        a2 = fmaf(w, p1.x, a2);
        a3 = fmaf(w, p1.y, a3);
        a4 = fmaf(w, p2.x, a4);
        a5 = fmaf(w, p2.y, a5);
        a6 = fmaf(w, p3.x, a6);
        a7 = fmaf(w, p3.y, a7);
        sA = sB; avA = avB; zpA = zpB; sB = sC;
    }
#pragma unroll
    for (int m = 8; m <= 32; m <<= 1) {
        den += __shfl_xor(den, m, 64);
        a0 += __shfl_xor(a0, m, 64);
        a1 += __shfl_xor(a1, m, 64);
        a2 += __shfl_xor(a2, m, 64);
        a3 += __shfl_xor(a3, m, 64);
        a4 += __shfl_xor(a4, m, 64);
        a5 += __shfl_xor(a5, m, 64);
        a6 += __shfl_xor(a6, m, 64);
        a7 += __shfl_xor(a7, m, 64);
    }
    if (g == 0) {
        const int c = 8 * q;
        float o0 = bflo(hv4.x) + bg[c + 0], o1 = bfhi(hv4.x) + bg[c + 1];
        float o2 = bflo(hv4.y) + bg[c + 2], o3 = bfhi(hv4.y) + bg[c + 3];
        float o4 = bflo(hv4.z) + bg[c + 4], o5 = bfhi(hv4.z) + bg[c + 5];
        float o6 = bflo(hv4.w) + bg[c + 6], o7 = bfhi(hv4.w) + bg[c + 7];
        if (r1 > r0) {
            const float rds = (1.f / den) * ZISC;   // fold fp8 scale
            o0 = fmaf(a0, rds, o0); o1 = fmaf(a1, rds, o1);
            o2 = fmaf(a2, rds, o2); o3 = fmaf(a3, rds, o3);
            o4 = fmaf(a4, rds, o4); o5 = fmaf(a5, rds, o5);
            o6 = fmaf(a6, rds, o6); o7 = fmaf(a7, rds, o7);
        }
        const uint4 ov = make_uint4(f2bf(o0) | (f2bf(o1) << 16),
                                    f2bf(o2) | (f2bf(o3) << 16),
                                    f2bf(o4) | (f2bf(o5) << 16),
                                    f2bf(o6) | (f2bf(o7) << 16));
        *(uint4*)(hout32 + (size_t)d * 32 + 4 * q) = ov;
    }
}

// LayerNorm + out = hn @ W_out + b_out. W column in registers; h bf16 in.
__global__ __launch_bounds__(256, 4)
void k_ln_out(const unsigned short* __restrict__ h16, const float* __restrict__ g,
              const float* __restrict__ be, const float* __restrict__ Wo,
              const float* __restrict__ bo, float* __restrict__ out) {
    const int j = threadIdx.x & 63;
    float Wreg[HID];
#pragma unroll
    for (int k = 0; k < HID; ++k) Wreg[k] = Wo[k * OUT_DIM + j];
    const float gj = g[j], bej = be[j], boj = bo[j];
    const int wid = (blockIdx.x * blockDim.x + threadIdx.x) >> 6;
    const int nw  = (gridDim.x * blockDim.x) >> 6;
    for (int v0 = wid * RB; v0 < NN; v0 += nw * RB) {
        float hn[RB];
#pragma unroll
        for (int r = 0; r < RB; ++r) {
            const float x = bf2f(h16[(size_t)(v0 + r) * HID + j]);
            float s = x;
#pragma unroll
            for (int m = 32; m >= 1; m >>= 1) s += __shfl_xor(s, m, 64);
            const float mu = s * (1.f / 64.f);
            const float dx = x - mu;
            float vs = dx * dx;
#pragma unroll
            for (int m = 32; m >= 1; m >>= 1) vs += __shfl_xor(vs, m, 64);
            hn[r] = dx * rsqrtf(vs * (1.f / 64.f) + LN_EPS) * gj + bej;
        }
        float acc[RB];
#pragma unroll
        for (int r = 0; r < RB; ++r) acc[r] = boj;
#pragma unroll
        for (int k = 0; k < HID; ++k) {
#pragma unroll
            for (int r = 0; r < RB; ++r)
                acc[r] = fmaf(bcast(hn[r], k), Wreg[k], acc[r]);
        }
#pragma unroll
        for (int r = 0; r < RB; ++r) out[(size_t)(v0 + r) * OUT_DIM + j] = acc[r];
    }
}

extern "C" void kernel_launch(void* const* d_in, const int* in_sizes, int n_in,
                              void* d_out, int out_size, void* d_ws, size_t ws_size,
                              hipStream_t stream) {
    const float* X     = (const float*)d_in[0];
    const int*   src   = (const int*)d_in[1];
    const int*   dst   = (const int*)d_in[2];
    const float* W_in  = (const float*)d_in[3];
    const float* b_in  = (const float*)d_in[4];
    // d_in[5..8]: rewiring MLP params — output is dead, skipped entirely
    const float* W_gat = (const float*)d_in[9];
    const float* a_l   = (const float*)d_in[10];
    const float* a_r   = (const float*)d_in[11];
    const float* b_gat = (const float*)d_in[12];
    const float* ln_g  = (const float*)d_in[13];
    const float* ln_b  = (const float*)d_in[14];
    const float* W_out = (const float*)d_in[15];
    const float* b_out = (const float*)d_in[16];
    float* out = (float*)d_out;

    char* ws = (char*)d_ws;
    unsigned short* hA16 = (unsigned short*)ws;                    // N*64 bf16 (12.8MB)
    unsigned short* hB16 = hA16 + (size_t)NN * HID;                // N*64 bf16 (12.8MB)
    unsigned* zb8 = (unsigned*)(hB16 + (size_t)NN * HID);          // N*16 dwords fp8 (6.4MB)
    float* el = (float*)(zb8 + (size_t)NN * 16);                   // N*4
    float* er = el + (size_t)NN * NH;                              // N*4
    int* rowptr = (int*)(er + (size_t)NN * NH);                    // N+1
    int* esrc   = rowptr + NN + 1;                                 // E + 32 (padded)
    int* bcnt   = esrc + EE + 32;
    uintptr_t wp = (uintptr_t)(bcnt + NB);
    wp = (wp + 15) & ~(uintptr_t)15;
    uint4* Wb   = (uint4*)wp;                                      // 16 KB
    uint4* Wbg  = Wb + 1024;                                       // 30 KB
    unsigned* bbuf = (unsigned*)hB16;   // aliases hB16 (dead until after CSR build)

    k_prep<<<14, 256, 0, stream>>>(W_in, W_gat, a_l, a_r, Wb, Wbg, bcnt, esrc + EE);
    k_in_gemm<<<(NN + 63) / 64, 256, 0, stream>>>(X, Wb, b_in, (unsigned*)hA16);
    k_bucketize<<<P1_BLOCKS, 256, 0, stream>>>(src, dst, bcnt, bbuf);
    k_localcsr<<<NB, 256, 0, stream>>>(bcnt, bbuf, rowptr, esrc);

    unsigned short* hin = hA16;
    unsigned short* hout = hB16;
    for (int l = 0; l < NL; ++l) {
        k_zgemm<<<(NN + 63) / 64, 256, 0, stream>>>(hin, Wbg + (size_t)l * 640,
                                                    zb8, el, er);
        k_gat_dst<<<(NN + 3) / 4, 256, 0, stream>>>(rowptr, esrc, el, er,
                                                    (const uint2*)zb8, hin,
                                                    b_gat + (size_t)l * HID,
                                                    (unsigned*)hout);
        unsigned short* t = hin; hin = hout; hout = t;
    }

    k_ln_out<<<1024, 256, 0, stream>>>(hin, ln_g, ln_b, W_out, b_out, out);
}